// Round 13
// baseline (2280.410 us; speedup 1.0000x reference)
//
#include <hip/hip_runtime.h>
#include <math.h>

#define BATCH 8
#define NPTS 4096
#define MM1 2048
#define MM2 512
#define KNBR 32
#define BQCAP 256   // ball-query candidate cap (expected hits ~5-10; tail past 256 ~ 0)

// ---- wave64 max via DPP + readlane broadcast (no DS). Proven exact R8-R12.
__device__ __forceinline__ unsigned int wave64_max_u32(unsigned int v) {
    unsigned int o;
    o = (unsigned)__builtin_amdgcn_update_dpp(0, (int)v, 0x111, 0xf, 0xf, true); // row_shr:1
    v = (o > v) ? o : v;
    o = (unsigned)__builtin_amdgcn_update_dpp(0, (int)v, 0x112, 0xf, 0xf, true); // row_shr:2
    v = (o > v) ? o : v;
    o = (unsigned)__builtin_amdgcn_update_dpp(0, (int)v, 0x114, 0xf, 0xf, true); // row_shr:4
    v = (o > v) ? o : v;
    o = (unsigned)__builtin_amdgcn_update_dpp(0, (int)v, 0x118, 0xf, 0xf, true); // row_shr:8
    v = (o > v) ? o : v;
    o = (unsigned)__builtin_amdgcn_update_dpp(0, (int)v, 0x142, 0xa, 0xf, true); // row_bcast:15
    v = (o > v) ? o : v;
    o = (unsigned)__builtin_amdgcn_update_dpp(0, (int)v, 0x143, 0xc, 0xf, true); // row_bcast:31
    v = (o > v) ? o : v;
    return (unsigned)__builtin_amdgcn_readlane((int)v, 63);
}

__device__ __forceinline__ float readlane_f(float v, int l) {
    return __uint_as_float((unsigned)__builtin_amdgcn_readlane((int)__float_as_uint(v), l));
}

// ---------------- FPS body (512 thr, 8 waves per batch-block) ----------------
// fp32 selection with fmaf dist (absmax 0.0 in R12; margins argument R1-R12).
// R13: break the post-barrier slot->sp[win] dependent-read chain (~240cy):
//  - winner coords extracted PRE-barrier from the winning lane's registers
//    (compile-time cndmask tree over jj, then readlane from lane l) and
//    published write-only to parity-double-buffered cand[2][8]
//  - atomic packs (key<<32)|((~idx)<<4)|wid ; tie order: max key, then max
//    ~idx (= min idx, first-max exact); wid can't flip (fields disjoint)
//  - post-barrier: slot read || 8 independent cand reads (one latency window),
//    then 7-select float4 tree by wid (~56cy issue)
// cand parity-2 safety: a straggler reading epoch-m's buffer blocks barrier
// m+1, which gates the next write to that same buffer (epoch m+2).
// slot keeps the proven 3-rotation re-arm.
template<int N, int PER, int MMAX>
__device__ void fps_body(const float* __restrict__ pos,
                         float* __restrict__ out_pos, int M) {
    const int b = blockIdx.x;
    const int tid = threadIdx.x;
    const int wid = tid >> 6;
    const int lane = tid & 63;
    __shared__ float4 sp[N];
    __shared__ int sel[MMAX];
    __shared__ unsigned long long slot[3];
    __shared__ float4 cand[2][8];

    const float* p = pos + (size_t)b * N * 3;
    for (int j = tid; j < N; j += 512)
        sp[j] = make_float4(p[j * 3 + 0], p[j * 3 + 1], p[j * 3 + 2], 0.0f);
    if (tid < 3) slot[tid] = 0ULL;
    __syncthreads();

    float ox[PER], oy[PER], oz[PER], dist[PER];
#pragma unroll
    for (int jj = 0; jj < PER; ++jj) {
        const float4 q = sp[tid * PER + jj];
        ox[jj] = q.x; oy[jj] = q.y; oz[jj] = q.z;
        dist[jj] = __int_as_float(0x7f800000);  // +inf
    }

    int last = 0;
    float lx = sp[0].x, ly = sp[0].y, lz = sp[0].z;
    int cur = 0;
    for (int m = 0; m < M; ++m) {
        const int par = m & 1;
        if (tid == 0) {
            sel[m] = last;
            slot[cur == 2 ? 0 : cur + 1] = 0ULL;  // re-arm slot for iter m+1
        }

        unsigned int bk;  // best key = fp32 bits (monotone u32 for d >= 0)
        int bi;
        {
            const float dx = ox[0] - lx;
            const float dy = oy[0] - ly;
            const float dz = oz[0] - lz;
            const float dd = fmaf(dz, dz, fmaf(dy, dy, dx * dx));
            const float dm = fminf(dd, dist[0]);
            dist[0] = dm;
            bk = __float_as_uint(dm);
            bi = tid * PER;
        }
#pragma unroll
        for (int jj = 1; jj < PER; ++jj) {
            const float dx = ox[jj] - lx;
            const float dy = oy[jj] - ly;
            const float dz = oz[jj] - lz;
            const float dd = fmaf(dz, dz, fmaf(dy, dy, dx * dx));
            const float dm = fminf(dd, dist[jj]);
            dist[jj] = dm;
            const unsigned int k = __float_as_uint(dm);
            if (k > bk) { bk = k; bi = tid * PER + jj; }  // strict >: first-max
        }

        // wave max (DPP), first-max winner lane via ballot+ffs
        const unsigned int mx = wave64_max_u32(bk);
        const unsigned long long cmask = __ballot(bk == mx);
        const int l = __ffsll((long long)cmask) - 1;
        const int wbi = __builtin_amdgcn_readlane(bi, l);

        // winner coords from lane l's registers: jjw is wave-uniform;
        // compile-time-unrolled select tree (no runtime reg indexing)
        const int jjw = wbi & (PER - 1);
        float sx_ = ox[0], sy_ = oy[0], sz_ = oz[0];
#pragma unroll
        for (int jj = 1; jj < PER; ++jj) {
            const bool pick = (jjw == jj);
            sx_ = pick ? ox[jj] : sx_;
            sy_ = pick ? oy[jj] : sy_;
            sz_ = pick ? oz[jj] : sz_;
        }
        const float wx_ = readlane_f(sx_, l);
        const float wy_ = readlane_f(sy_, l);
        const float wz_ = readlane_f(sz_, l);

        if (lane == 0) {
            cand[par][wid] = make_float4(wx_, wy_, wz_, 0.0f);
            atomicMax(&slot[cur],
                      ((unsigned long long)mx << 32) |
                      (((unsigned int)(~wbi) << 4) | (unsigned int)wid));
        }
        __syncthreads();

        // post-barrier: slot + all 8 cand reads issue in one latency window
        const unsigned long long pk = slot[cur];
        const float4 c0 = cand[par][0], c1 = cand[par][1];
        const float4 c2 = cand[par][2], c3 = cand[par][3];
        const float4 c4 = cand[par][4], c5 = cand[par][5];
        const float4 c6 = cand[par][6], c7 = cand[par][7];
        const unsigned int lo = (unsigned int)pk;
        const int wwid = (int)(lo & 15u);
        const int win = (int)((~(lo >> 4)) & 0x0FFFFFFFu);
        // 7-select float4 tree by wwid bits
        const float4 t0 = (wwid & 1) ? c1 : c0;
        const float4 t1 = (wwid & 1) ? c3 : c2;
        const float4 t2 = (wwid & 1) ? c5 : c4;
        const float4 t3 = (wwid & 1) ? c7 : c6;
        const float4 u0 = (wwid & 2) ? t1 : t0;
        const float4 u1 = (wwid & 2) ? t3 : t2;
        const float4 wq = (wwid & 4) ? u1 : u0;

        last = win;
        lx = wq.x; ly = wq.y; lz = wq.z;
        cur = (cur == 2) ? 0 : cur + 1;
    }
    __syncthreads();
    for (int m = tid; m < M; m += 512) {
        const float4 q = sp[sel[m]];
        out_pos[((size_t)(b * M + m)) * 3 + 0] = q.x;
        out_pos[((size_t)(b * M + m)) * 3 + 1] = q.y;
        out_pos[((size_t)(b * M + m)) * 3 + 2] = q.z;
    }
}

// ---------------- mlp1 body: pointwise, one wave per point (8 waves/block) ----------------
__device__ void mlp1_body(const float* __restrict__ pos,
                          const float* __restrict__ w1a, const float* __restrict__ b1a,
                          const float* __restrict__ w1b, const float* __restrict__ b1b,
                          float* __restrict__ h, int blk) {
    __shared__ float t1[8][64];
    const int wslot = threadIdx.x >> 6;
    const int lane = threadIdx.x & 63;
    const int pt = blk * 8 + wslot;            // < BATCH*NPTS by grid construction
    const float px = pos[pt * 3 + 0], py = pos[pt * 3 + 1], pz = pos[pt * 3 + 2];
    float acc = b1a[lane];
    acc = fmaf(px, w1a[0 * 64 + lane], acc);
    acc = fmaf(py, w1a[1 * 64 + lane], acc);
    acc = fmaf(pz, w1a[2 * 64 + lane], acc);
    t1[wslot][lane] = fmaxf(acc, 0.0f);
    __builtin_amdgcn_wave_barrier();
    float acc2 = b1b[lane];
    for (int i = 0; i < 64; ++i) acc2 = fmaf(t1[wslot][i], w1b[i * 64 + lane], acc2);
    h[(size_t)pt * 64 + lane] = acc2;
}

// ---------------- ball query body: one wave per center (8 waves/block; proven R7-R12) ----------------
template<int N>
__device__ void ballq_body(const float* __restrict__ pos, const float* __restrict__ ctr,
                           int* __restrict__ nbr, int M, double rr, int blk) {
    const int wslot = threadIdx.x >> 6;
    const int lane = threadIdx.x & 63;
    const int c = blk * 8 + wslot;             // global center id = b*M + m
    const int b = c / M;

    __shared__ double cd2[8][BQCAP];
    __shared__ int cidx[8][BQCAP];

    const double cx = (double)ctr[c * 3 + 0];
    const double cy = (double)ctr[c * 3 + 1];
    const double cz = (double)ctr[c * 3 + 2];
    const float* p = pos + (size_t)b * N * 3;
    const unsigned long long below = (1ULL << lane) - 1ULL;

    int cnt = 0;
    for (int base = 0; base < N; base += 64) {
        const int j = base + lane;
        const double dx = (double)p[j * 3 + 0] - cx;
        const double dy = (double)p[j * 3 + 1] - cy;
        const double dz = (double)p[j * 3 + 2] - cz;
        const double d2 = dx * dx + dy * dy + dz * dz;
        const bool hit = (d2 <= rr);
        const unsigned long long mask = __ballot(hit);
        if (hit) {
            const int ofs = cnt + (int)__popcll(mask & below);
            if (ofs < BQCAP) { cd2[wslot][ofs] = d2; cidx[wslot][ofs] = j; }
        }
        cnt += (int)__popcll(mask);
    }
    __builtin_amdgcn_wave_barrier();

    int* outp = nbr + (size_t)c * KNBR;
    if (cnt <= KNBR) {
        if (lane < KNBR) outp[lane] = (lane < cnt) ? cidx[wslot][lane] : -1;
    } else {
        if (cnt > BQCAP) cnt = BQCAP;
        for (int i = lane; i < cnt; i += 64) {
            const double di = cd2[wslot][i];
            const int ii = cidx[wslot][i];
            int rank = 0;
            for (int t = 0; t < cnt; ++t) {
                const double dt = cd2[wslot][t];
                rank += (dt < di) || (dt == di && cidx[wslot][t] < ii);
            }
            if (rank < KNBR) outp[rank] = ii;
        }
    }
}

// ---------------- agg1+mlp2 body: one wave per SA1 center (8 waves/block) ----------------
__device__ void aggmlp_body(const float* __restrict__ h, const int* __restrict__ nbr1,
                            const float* __restrict__ w2a, const float* __restrict__ b2a,
                            const float* __restrict__ w2b, const float* __restrict__ b2b,
                            float* __restrict__ h2, int blk) {
    __shared__ float xrow[8][64];
    __shared__ float trow[8][128];
    const int wslot = threadIdx.x >> 6;
    const int lane = threadIdx.x & 63;
    const int c = blk * 8 + wslot;             // global SA1-center id = b*MM1 + m
    const int b = c / MM1;

    const int* nb = nbr1 + (size_t)c * KNBR;
    int idxs[KNBR];
#pragma unroll
    for (int k = 0; k < KNBR; ++k) idxs[k] = nb[k];
    float acc = -INFINITY;
#pragma unroll
    for (int k = 0; k < KNBR; ++k) {
        const int idx = idxs[k];
        if (idx >= 0) acc = fmaxf(acc, h[((size_t)b * NPTS + idx) * 64 + lane]);
    }
    xrow[wslot][lane] = acc;
    __builtin_amdgcn_wave_barrier();

#pragma unroll
    for (int half = 0; half < 2; ++half) {
        const int co = lane + half * 64;
        float a2 = b2a[co];
        for (int i = 0; i < 64; ++i) a2 = fmaf(xrow[wslot][i], w2a[i * 128 + co], a2);
        trow[wslot][co] = fmaxf(a2, 0.0f);
    }
    __builtin_amdgcn_wave_barrier();

#pragma unroll
    for (int half = 0; half < 2; ++half) {
        const int co = lane + half * 64;
        float a3 = b2b[co];
        for (int i = 0; i < 128; ++i) a3 = fmaf(trow[wslot][i], w2b[i * 128 + co], a3);
        h2[(size_t)c * 128 + co] = a3;
    }
}

// ---------------- fused launches (512 threads) ----------------
template<int N, int PER, int MMAX>
__global__ __launch_bounds__(512, 1) void fps_mlp1_kernel(
        const float* __restrict__ pos, float* __restrict__ out_pos, int M,
        const float* __restrict__ w1a, const float* __restrict__ b1a,
        const float* __restrict__ w1b, const float* __restrict__ b1b,
        float* __restrict__ h) {
    if (blockIdx.x < BATCH) fps_body<N, PER, MMAX>(pos, out_pos, M);
    else mlp1_body(pos, w1a, b1a, w1b, b1b, h, blockIdx.x - BATCH);
}

template<int NF, int PER, int MMAX, int NB>
__global__ __launch_bounds__(512, 1) void fps_ballq_kernel(
        const float* __restrict__ fpos, float* __restrict__ fout, int FM,
        const float* __restrict__ bpos, const float* __restrict__ bctr,
        int* __restrict__ nbr, int BM, double rr) {
    if (blockIdx.x < BATCH) fps_body<NF, PER, MMAX>(fpos, fout, FM);
    else ballq_body<NB>(bpos, bctr, nbr, BM, rr, blockIdx.x - BATCH);
}

template<int NB>
__global__ __launch_bounds__(512, 1) void aggmlp_ballq_kernel(
        const float* __restrict__ h, const int* __restrict__ nbr1,
        const float* __restrict__ w2a, const float* __restrict__ b2a,
        const float* __restrict__ w2b, const float* __restrict__ b2b,
        float* __restrict__ h2, int aggmlp_blocks,
        const float* __restrict__ bpos, const float* __restrict__ bctr,
        int* __restrict__ nbr2, int BM, double rr) {
    if ((int)blockIdx.x < aggmlp_blocks)
        aggmlp_body(h, nbr1, w2a, b2a, w2b, b2b, h2, blockIdx.x);
    else
        ballq_body<NB>(bpos, bctr, nbr2, BM, rr, blockIdx.x - aggmlp_blocks);
}

// ---------------- max aggregation (SA2): one wave per center ----------------
__global__ __launch_bounds__(256) void agg_kernel(const float* __restrict__ h,
                                                  const int* __restrict__ nbr,
                                                  float* __restrict__ out,
                                                  int N, int M, int C) {
    const int wave = (blockIdx.x * blockDim.x + threadIdx.x) >> 6;
    const int lane = threadIdx.x & 63;
    if (wave >= BATCH * M) return;
    const int b = wave / M;
    const int m = wave - b * M;
    const int* nb = nbr + (size_t)(b * M + m) * KNBR;
    int idxs[KNBR];
#pragma unroll
    for (int k = 0; k < KNBR; ++k) idxs[k] = nb[k];
    for (int c = lane; c < C; c += 64) {
        float acc = -INFINITY;
#pragma unroll
        for (int k = 0; k < KNBR; ++k) {
            const int idx = idxs[k];
            if (idx >= 0) acc = fmaxf(acc, h[((size_t)b * N + idx) * C + c]);
        }
        out[((size_t)(b * M + m)) * C + c] = acc;
    }
}

// ---------------- head: global max pool + MLPs + log_softmax ----------------
__global__ __launch_bounds__(256) void head_kernel(const float* __restrict__ x2,
                                                   const float* __restrict__ w3a, const float* __restrict__ b3a,
                                                   const float* __restrict__ w3b, const float* __restrict__ b3b,
                                                   const float* __restrict__ fc1w, const float* __restrict__ fc1b,
                                                   const float* __restrict__ fc2w, const float* __restrict__ fc2b,
                                                   float* __restrict__ out) {
    const int b = blockIdx.x;
    const int tid = threadIdx.x;
    __shared__ float g[128], t1[256], t2[512], t3[256], logits[16];

    if (tid < 128) {
        float acc = -INFINITY;
        for (int m = 0; m < MM2; ++m) acc = fmaxf(acc, x2[((size_t)(b * MM2 + m)) * 128 + tid]);
        g[tid] = acc;
    }
    __syncthreads();
    {   // 128 -> 256, relu
        float acc = b3a[tid];
        for (int i = 0; i < 128; ++i) acc = fmaf(g[i], w3a[i * 256 + tid], acc);
        t1[tid] = fmaxf(acc, 0.0f);
    }
    __syncthreads();
    for (int c = tid; c < 512; c += 256) {  // 256 -> 512, no relu
        float acc = b3b[c];
        for (int i = 0; i < 256; ++i) acc = fmaf(t1[i], w3b[i * 512 + c], acc);
        t2[c] = acc;
    }
    __syncthreads();
    {   // 512 -> 256, relu
        float acc = fc1b[tid];
        for (int i = 0; i < 512; ++i) acc = fmaf(t2[i], fc1w[i * 256 + tid], acc);
        t3[tid] = fmaxf(acc, 0.0f);
    }
    __syncthreads();
    if (tid < 10) {  // 256 -> 10
        float acc = fc2b[tid];
        for (int i = 0; i < 256; ++i) acc = fmaf(t3[i], fc2w[i * 10 + tid], acc);
        logits[tid] = acc;
    }
    __syncthreads();
    if (tid == 0) {
        float mx = logits[0];
        for (int i = 1; i < 10; ++i) mx = fmaxf(mx, logits[i]);
        float s = 0.0f;
        for (int i = 0; i < 10; ++i) s += expf(logits[i] - mx);
        const float lse = mx + logf(s);
        for (int i = 0; i < 10; ++i) out[b * 10 + i] = logits[i] - lse;
    }
}

extern "C" void kernel_launch(void* const* d_in, const int* in_sizes, int n_in,
                              void* d_out, int out_size, void* d_ws, size_t ws_size,
                              hipStream_t stream) {
    const float* pos  = (const float*)d_in[0];
    const float* w1a  = (const float*)d_in[1];
    const float* b1a  = (const float*)d_in[2];
    const float* w1b  = (const float*)d_in[3];
    const float* b1b  = (const float*)d_in[4];
    const float* w2a  = (const float*)d_in[5];
    const float* b2a  = (const float*)d_in[6];
    const float* w2b  = (const float*)d_in[7];
    const float* b2b  = (const float*)d_in[8];
    const float* w3a  = (const float*)d_in[9];
    const float* b3a  = (const float*)d_in[10];
    const float* w3b  = (const float*)d_in[11];
    const float* b3b  = (const float*)d_in[12];
    const float* fc1w = (const float*)d_in[13];
    const float* fc1b = (const float*)d_in[14];
    const float* fc2w = (const float*)d_in[15];
    const float* fc2b = (const float*)d_in[16];

    char* ws = (char*)d_ws;
    float* pos1 = (float*)(ws + (64 << 10));        // 192 KB  [8,2048,3]
    float* pos2 = (float*)(ws + (272 << 10));       //  48 KB  [8,512,3]
    int*   nbr1 = (int*)  (ws + (320 << 10));       //   2 MB  [8,2048,32]
    int*   nbr2 = (int*)  (ws + (2368 << 10));      // 512 KB  [8,512,32]
    float* x2   = (float*)(ws + (7  << 20));        //   2 MB  [8,512,128]
    float* h2   = (float*)(ws + (9  << 20));        //   8 MB  [8,2048,128]
    float* h    = (float*)(ws + (17 << 20));        //   8 MB  [8,4096,64]

    const int MLP1 = (BATCH * NPTS) / 8;            // 4096 blocks (8 pts/block)
    const int BQ1  = (BATCH * MM1) / 8;             // 2048 blocks
    const int AGM  = (BATCH * MM1) / 8;             // 2048 blocks
    const int BQ2  = (BATCH * MM2) / 8;             // 512 blocks
    const int AG2  = (BATCH * MM2) / 4;             // 1024 blocks (agg_kernel, 256 thr)

    // K1: fps1 (blocks 0-7) || mlp1 (pos -> h)
    fps_mlp1_kernel<NPTS, NPTS / 512, MM1><<<BATCH + MLP1, 512, 0, stream>>>(
        pos, pos1, MM1, w1a, b1a, w1b, b1b, h);
    // K2: fps2 (blocks 0-7, pos1 -> pos2) || ballq1 (pos, pos1 -> nbr1)
    fps_ballq_kernel<MM1, MM1 / 512, MM2, NPTS><<<BATCH + BQ1, 512, 0, stream>>>(
        pos1, pos2, MM2, pos, pos1, nbr1, MM1, 0.2 * 0.2);
    // K3: agg1+mlp2 (h, nbr1 -> h2) || ballq2 (pos1, pos2 -> nbr2)
    aggmlp_ballq_kernel<MM1><<<AGM + BQ2, 512, 0, stream>>>(
        h, nbr1, w2a, b2a, w2b, b2b, h2, AGM,
        pos1, pos2, nbr2, MM2, 0.4 * 0.4);
    // K4: agg2 (h2, nbr2 -> x2)
    agg_kernel<<<AG2, 256, 0, stream>>>(h2, nbr2, x2, MM1, MM2, 128);
    // K5: head
    head_kernel<<<BATCH, 256, 0, stream>>>(x2, w3a, b3a, w3b, b3b, fc1w, fc1b, fc2w, fc2b,
                                           (float*)d_out);
}

// Round 14
// 1309.953 us; speedup vs baseline: 1.7408x; 1.7408x over previous
//
#include <hip/hip_runtime.h>
#include <math.h>

#define BATCH 8
#define NPTS 4096
#define MM1 2048
#define MM2 512
#define KNBR 32
#define BQCAP 256   // ball-query candidate cap (expected hits ~5-10; tail past 256 ~ 0)

// ---- wave64 max via DPP + readlane broadcast (no DS). Proven exact R8-R12.
__device__ __forceinline__ unsigned int wave64_max_u32(unsigned int v) {
    unsigned int o;
    o = (unsigned)__builtin_amdgcn_update_dpp(0, (int)v, 0x111, 0xf, 0xf, true); // row_shr:1
    v = (o > v) ? o : v;
    o = (unsigned)__builtin_amdgcn_update_dpp(0, (int)v, 0x112, 0xf, 0xf, true); // row_shr:2
    v = (o > v) ? o : v;
    o = (unsigned)__builtin_amdgcn_update_dpp(0, (int)v, 0x114, 0xf, 0xf, true); // row_shr:4
    v = (o > v) ? o : v;
    o = (unsigned)__builtin_amdgcn_update_dpp(0, (int)v, 0x118, 0xf, 0xf, true); // row_shr:8
    v = (o > v) ? o : v;
    o = (unsigned)__builtin_amdgcn_update_dpp(0, (int)v, 0x142, 0xa, 0xf, true); // row_bcast:15
    v = (o > v) ? o : v;
    o = (unsigned)__builtin_amdgcn_update_dpp(0, (int)v, 0x143, 0xc, 0xf, true); // row_bcast:31
    v = (o > v) ? o : v;
    return (unsigned)__builtin_amdgcn_readlane((int)v, 63);
}

// ---------------- FPS body (512 thr, 8 waves per batch-block) ----------------
// R14 = exact revert to R12 (937us K1, absmax 0.0). R13's "publish winner
// coords to cand[2][8], read all 8 post-barrier" REGRESSED +800cy/iter:
// 9 DS instruction issues per wave per iteration (~72/CU ~ 860cy DS-pipe
// occupancy) -- broadcast LDS reads cost issue bandwidth even without
// conflicts. R12's 2-DS-inst path (slot b64 -> sp[win] b128) is the local
// optimum of this structure.
// fp32 selection with fmaf dist (absmax 0.0 R12; margins argument R1-R12).
// Block reduce: single LDS u64 atomicMax of (key<<32)|~idx (first-max exact);
// 3-slot rotation re-arm (two-barrier separation). Proven R11/R12.
template<int N, int PER, int MMAX>
__device__ void fps_body(const float* __restrict__ pos,
                         float* __restrict__ out_pos, int M) {
    const int b = blockIdx.x;
    const int tid = threadIdx.x;
    const int lane = tid & 63;
    __shared__ float4 sp[N];          // points as float4 -> winner coords in one b128 read
    __shared__ int sel[MMAX];
    __shared__ unsigned long long slot[3];

    const float* p = pos + (size_t)b * N * 3;
    for (int j = tid; j < N; j += 512)
        sp[j] = make_float4(p[j * 3 + 0], p[j * 3 + 1], p[j * 3 + 2], 0.0f);
    if (tid < 3) slot[tid] = 0ULL;
    __syncthreads();

    float ox[PER], oy[PER], oz[PER], dist[PER];
#pragma unroll
    for (int jj = 0; jj < PER; ++jj) {
        const float4 q = sp[tid * PER + jj];
        ox[jj] = q.x; oy[jj] = q.y; oz[jj] = q.z;
        dist[jj] = __int_as_float(0x7f800000);  // +inf
    }

    int last = 0;
    float lx = sp[0].x, ly = sp[0].y, lz = sp[0].z;
    int cur = 0;
    for (int m = 0; m < M; ++m) {
        if (tid == 0) {
            sel[m] = last;
            slot[cur == 2 ? 0 : cur + 1] = 0ULL;  // re-arm slot for iter m+1
        }

        unsigned int bk;  // best key = fp32 bits (monotone u32 for d >= 0)
        int bi;
        {
            const float dx = ox[0] - lx;
            const float dy = oy[0] - ly;
            const float dz = oz[0] - lz;
            const float dd = fmaf(dz, dz, fmaf(dy, dy, dx * dx));
            const float dm = fminf(dd, dist[0]);
            dist[0] = dm;
            bk = __float_as_uint(dm);
            bi = tid * PER;
        }
#pragma unroll
        for (int jj = 1; jj < PER; ++jj) {
            const float dx = ox[jj] - lx;
            const float dy = oy[jj] - ly;
            const float dz = oz[jj] - lz;
            const float dd = fmaf(dz, dz, fmaf(dy, dy, dx * dx));
            const float dm = fminf(dd, dist[jj]);
            dist[jj] = dm;
            const unsigned int k = __float_as_uint(dm);
            if (k > bk) { bk = k; bi = tid * PER + jj; }  // strict >: first-max
        }

        // wave max (DPP), first-max winner lane via ballot+ffs (lane order == index order)
        const unsigned int mx = wave64_max_u32(bk);
        const unsigned long long cand = __ballot(bk == mx);
        const int l = __ffsll((long long)cand) - 1;
        const int wbi = __builtin_amdgcn_readlane(bi, l);

        // one atomic per wave into the shared slot
        if (lane == 0)
            atomicMax(&slot[cur], ((unsigned long long)mx << 32) | (unsigned int)(~wbi));
        __syncthreads();

        const unsigned long long pk = slot[cur];
        const int win = (int)(~(unsigned int)pk);
        const float4 wq = sp[win];
        last = win;
        lx = wq.x; ly = wq.y; lz = wq.z;
        cur = (cur == 2) ? 0 : cur + 1;
    }
    __syncthreads();
    for (int m = tid; m < M; m += 512) {
        const float4 q = sp[sel[m]];
        out_pos[((size_t)(b * M + m)) * 3 + 0] = q.x;
        out_pos[((size_t)(b * M + m)) * 3 + 1] = q.y;
        out_pos[((size_t)(b * M + m)) * 3 + 2] = q.z;
    }
}

// ---------------- mlp1 body: pointwise, one wave per point (8 waves/block) ----------------
__device__ void mlp1_body(const float* __restrict__ pos,
                          const float* __restrict__ w1a, const float* __restrict__ b1a,
                          const float* __restrict__ w1b, const float* __restrict__ b1b,
                          float* __restrict__ h, int blk) {
    __shared__ float t1[8][64];
    const int wslot = threadIdx.x >> 6;
    const int lane = threadIdx.x & 63;
    const int pt = blk * 8 + wslot;            // < BATCH*NPTS by grid construction
    const float px = pos[pt * 3 + 0], py = pos[pt * 3 + 1], pz = pos[pt * 3 + 2];
    float acc = b1a[lane];
    acc = fmaf(px, w1a[0 * 64 + lane], acc);
    acc = fmaf(py, w1a[1 * 64 + lane], acc);
    acc = fmaf(pz, w1a[2 * 64 + lane], acc);
    t1[wslot][lane] = fmaxf(acc, 0.0f);
    __builtin_amdgcn_wave_barrier();
    float acc2 = b1b[lane];
    for (int i = 0; i < 64; ++i) acc2 = fmaf(t1[wslot][i], w1b[i * 64 + lane], acc2);
    h[(size_t)pt * 64 + lane] = acc2;
}

// ---------------- ball query body: one wave per center (8 waves/block; proven R7-R12) ----------------
template<int N>
__device__ void ballq_body(const float* __restrict__ pos, const float* __restrict__ ctr,
                           int* __restrict__ nbr, int M, double rr, int blk) {
    const int wslot = threadIdx.x >> 6;
    const int lane = threadIdx.x & 63;
    const int c = blk * 8 + wslot;             // global center id = b*M + m
    const int b = c / M;

    __shared__ double cd2[8][BQCAP];
    __shared__ int cidx[8][BQCAP];

    const double cx = (double)ctr[c * 3 + 0];
    const double cy = (double)ctr[c * 3 + 1];
    const double cz = (double)ctr[c * 3 + 2];
    const float* p = pos + (size_t)b * N * 3;
    const unsigned long long below = (1ULL << lane) - 1ULL;

    int cnt = 0;
    for (int base = 0; base < N; base += 64) {
        const int j = base + lane;
        const double dx = (double)p[j * 3 + 0] - cx;
        const double dy = (double)p[j * 3 + 1] - cy;
        const double dz = (double)p[j * 3 + 2] - cz;
        const double d2 = dx * dx + dy * dy + dz * dz;
        const bool hit = (d2 <= rr);
        const unsigned long long mask = __ballot(hit);
        if (hit) {
            const int ofs = cnt + (int)__popcll(mask & below);
            if (ofs < BQCAP) { cd2[wslot][ofs] = d2; cidx[wslot][ofs] = j; }
        }
        cnt += (int)__popcll(mask);
    }
    __builtin_amdgcn_wave_barrier();

    int* outp = nbr + (size_t)c * KNBR;
    if (cnt <= KNBR) {
        if (lane < KNBR) outp[lane] = (lane < cnt) ? cidx[wslot][lane] : -1;
    } else {
        if (cnt > BQCAP) cnt = BQCAP;
        for (int i = lane; i < cnt; i += 64) {
            const double di = cd2[wslot][i];
            const int ii = cidx[wslot][i];
            int rank = 0;
            for (int t = 0; t < cnt; ++t) {
                const double dt = cd2[wslot][t];
                rank += (dt < di) || (dt == di && cidx[wslot][t] < ii);
            }
            if (rank < KNBR) outp[rank] = ii;
        }
    }
}

// ---------------- agg1+mlp2 body: one wave per SA1 center (8 waves/block) ----------------
__device__ void aggmlp_body(const float* __restrict__ h, const int* __restrict__ nbr1,
                            const float* __restrict__ w2a, const float* __restrict__ b2a,
                            const float* __restrict__ w2b, const float* __restrict__ b2b,
                            float* __restrict__ h2, int blk) {
    __shared__ float xrow[8][64];
    __shared__ float trow[8][128];
    const int wslot = threadIdx.x >> 6;
    const int lane = threadIdx.x & 63;
    const int c = blk * 8 + wslot;             // global SA1-center id = b*MM1 + m
    const int b = c / MM1;

    const int* nb = nbr1 + (size_t)c * KNBR;
    int idxs[KNBR];
#pragma unroll
    for (int k = 0; k < KNBR; ++k) idxs[k] = nb[k];
    float acc = -INFINITY;
#pragma unroll
    for (int k = 0; k < KNBR; ++k) {
        const int idx = idxs[k];
        if (idx >= 0) acc = fmaxf(acc, h[((size_t)b * NPTS + idx) * 64 + lane]);
    }
    xrow[wslot][lane] = acc;
    __builtin_amdgcn_wave_barrier();

#pragma unroll
    for (int half = 0; half < 2; ++half) {
        const int co = lane + half * 64;
        float a2 = b2a[co];
        for (int i = 0; i < 64; ++i) a2 = fmaf(xrow[wslot][i], w2a[i * 128 + co], a2);
        trow[wslot][co] = fmaxf(a2, 0.0f);
    }
    __builtin_amdgcn_wave_barrier();

#pragma unroll
    for (int half = 0; half < 2; ++half) {
        const int co = lane + half * 64;
        float a3 = b2b[co];
        for (int i = 0; i < 128; ++i) a3 = fmaf(trow[wslot][i], w2b[i * 128 + co], a3);
        h2[(size_t)c * 128 + co] = a3;
    }
}

// ---------------- fused launches (512 threads) ----------------
template<int N, int PER, int MMAX>
__global__ __launch_bounds__(512, 1) void fps_mlp1_kernel(
        const float* __restrict__ pos, float* __restrict__ out_pos, int M,
        const float* __restrict__ w1a, const float* __restrict__ b1a,
        const float* __restrict__ w1b, const float* __restrict__ b1b,
        float* __restrict__ h) {
    if (blockIdx.x < BATCH) fps_body<N, PER, MMAX>(pos, out_pos, M);
    else mlp1_body(pos, w1a, b1a, w1b, b1b, h, blockIdx.x - BATCH);
}

template<int NF, int PER, int MMAX, int NB>
__global__ __launch_bounds__(512, 1) void fps_ballq_kernel(
        const float* __restrict__ fpos, float* __restrict__ fout, int FM,
        const float* __restrict__ bpos, const float* __restrict__ bctr,
        int* __restrict__ nbr, int BM, double rr) {
    if (blockIdx.x < BATCH) fps_body<NF, PER, MMAX>(fpos, fout, FM);
    else ballq_body<NB>(bpos, bctr, nbr, BM, rr, blockIdx.x - BATCH);
}

template<int NB>
__global__ __launch_bounds__(512, 1) void aggmlp_ballq_kernel(
        const float* __restrict__ h, const int* __restrict__ nbr1,
        const float* __restrict__ w2a, const float* __restrict__ b2a,
        const float* __restrict__ w2b, const float* __restrict__ b2b,
        float* __restrict__ h2, int aggmlp_blocks,
        const float* __restrict__ bpos, const float* __restrict__ bctr,
        int* __restrict__ nbr2, int BM, double rr) {
    if ((int)blockIdx.x < aggmlp_blocks)
        aggmlp_body(h, nbr1, w2a, b2a, w2b, b2b, h2, blockIdx.x);
    else
        ballq_body<NB>(bpos, bctr, nbr2, BM, rr, blockIdx.x - aggmlp_blocks);
}

// ---------------- max aggregation (SA2): one wave per center ----------------
__global__ __launch_bounds__(256) void agg_kernel(const float* __restrict__ h,
                                                  const int* __restrict__ nbr,
                                                  float* __restrict__ out,
                                                  int N, int M, int C) {
    const int wave = (blockIdx.x * blockDim.x + threadIdx.x) >> 6;
    const int lane = threadIdx.x & 63;
    if (wave >= BATCH * M) return;
    const int b = wave / M;
    const int m = wave - b * M;
    const int* nb = nbr + (size_t)(b * M + m) * KNBR;
    int idxs[KNBR];
#pragma unroll
    for (int k = 0; k < KNBR; ++k) idxs[k] = nb[k];
    for (int c = lane; c < C; c += 64) {
        float acc = -INFINITY;
#pragma unroll
        for (int k = 0; k < KNBR; ++k) {
            const int idx = idxs[k];
            if (idx >= 0) acc = fmaxf(acc, h[((size_t)b * N + idx) * C + c]);
        }
        out[((size_t)(b * M + m)) * C + c] = acc;
    }
}

// ---------------- head: global max pool + MLPs + log_softmax ----------------
__global__ __launch_bounds__(256) void head_kernel(const float* __restrict__ x2,
                                                   const float* __restrict__ w3a, const float* __restrict__ b3a,
                                                   const float* __restrict__ w3b, const float* __restrict__ b3b,
                                                   const float* __restrict__ fc1w, const float* __restrict__ fc1b,
                                                   const float* __restrict__ fc2w, const float* __restrict__ fc2b,
                                                   float* __restrict__ out) {
    const int b = blockIdx.x;
    const int tid = threadIdx.x;
    __shared__ float g[128], t1[256], t2[512], t3[256], logits[16];

    if (tid < 128) {
        float acc = -INFINITY;
        for (int m = 0; m < MM2; ++m) acc = fmaxf(acc, x2[((size_t)(b * MM2 + m)) * 128 + tid]);
        g[tid] = acc;
    }
    __syncthreads();
    {   // 128 -> 256, relu
        float acc = b3a[tid];
        for (int i = 0; i < 128; ++i) acc = fmaf(g[i], w3a[i * 256 + tid], acc);
        t1[tid] = fmaxf(acc, 0.0f);
    }
    __syncthreads();
    for (int c = tid; c < 512; c += 256) {  // 256 -> 512, no relu
        float acc = b3b[c];
        for (int i = 0; i < 256; ++i) acc = fmaf(t1[i], w3b[i * 512 + c], acc);
        t2[c] = acc;
    }
    __syncthreads();
    {   // 512 -> 256, relu
        float acc = fc1b[tid];
        for (int i = 0; i < 512; ++i) acc = fmaf(t2[i], fc1w[i * 256 + tid], acc);
        t3[tid] = fmaxf(acc, 0.0f);
    }
    __syncthreads();
    if (tid < 10) {  // 256 -> 10
        float acc = fc2b[tid];
        for (int i = 0; i < 256; ++i) acc = fmaf(t3[i], fc2w[i * 10 + tid], acc);
        logits[tid] = acc;
    }
    __syncthreads();
    if (tid == 0) {
        float mx = logits[0];
        for (int i = 1; i < 10; ++i) mx = fmaxf(mx, logits[i]);
        float s = 0.0f;
        for (int i = 0; i < 10; ++i) s += expf(logits[i] - mx);
        const float lse = mx + logf(s);
        for (int i = 0; i < 10; ++i) out[b * 10 + i] = logits[i] - lse;
    }
}

extern "C" void kernel_launch(void* const* d_in, const int* in_sizes, int n_in,
                              void* d_out, int out_size, void* d_ws, size_t ws_size,
                              hipStream_t stream) {
    const float* pos  = (const float*)d_in[0];
    const float* w1a  = (const float*)d_in[1];
    const float* b1a  = (const float*)d_in[2];
    const float* w1b  = (const float*)d_in[3];
    const float* b1b  = (const float*)d_in[4];
    const float* w2a  = (const float*)d_in[5];
    const float* b2a  = (const float*)d_in[6];
    const float* w2b  = (const float*)d_in[7];
    const float* b2b  = (const float*)d_in[8];
    const float* w3a  = (const float*)d_in[9];
    const float* b3a  = (const float*)d_in[10];
    const float* w3b  = (const float*)d_in[11];
    const float* b3b  = (const float*)d_in[12];
    const float* fc1w = (const float*)d_in[13];
    const float* fc1b = (const float*)d_in[14];
    const float* fc2w = (const float*)d_in[15];
    const float* fc2b = (const float*)d_in[16];

    char* ws = (char*)d_ws;
    float* pos1 = (float*)(ws + (64 << 10));        // 192 KB  [8,2048,3]
    float* pos2 = (float*)(ws + (272 << 10));       //  48 KB  [8,512,3]
    int*   nbr1 = (int*)  (ws + (320 << 10));       //   2 MB  [8,2048,32]
    int*   nbr2 = (int*)  (ws + (2368 << 10));      // 512 KB  [8,512,32]
    float* x2   = (float*)(ws + (7  << 20));        //   2 MB  [8,512,128]
    float* h2   = (float*)(ws + (9  << 20));        //   8 MB  [8,2048,128]
    float* h    = (float*)(ws + (17 << 20));        //   8 MB  [8,4096,64]

    const int MLP1 = (BATCH * NPTS) / 8;            // 4096 blocks (8 pts/block)
    const int BQ1  = (BATCH * MM1) / 8;             // 2048 blocks
    const int AGM  = (BATCH * MM1) / 8;             // 2048 blocks
    const int BQ2  = (BATCH * MM2) / 8;             // 512 blocks
    const int AG2  = (BATCH * MM2) / 4;             // 1024 blocks (agg_kernel, 256 thr)

    // K1: fps1 (blocks 0-7) || mlp1 (pos -> h)
    fps_mlp1_kernel<NPTS, NPTS / 512, MM1><<<BATCH + MLP1, 512, 0, stream>>>(
        pos, pos1, MM1, w1a, b1a, w1b, b1b, h);
    // K2: fps2 (blocks 0-7, pos1 -> pos2) || ballq1 (pos, pos1 -> nbr1)
    fps_ballq_kernel<MM1, MM1 / 512, MM2, NPTS><<<BATCH + BQ1, 512, 0, stream>>>(
        pos1, pos2, MM2, pos, pos1, nbr1, MM1, 0.2 * 0.2);
    // K3: agg1+mlp2 (h, nbr1 -> h2) || ballq2 (pos1, pos2 -> nbr2)
    aggmlp_ballq_kernel<MM1><<<AGM + BQ2, 512, 0, stream>>>(
        h, nbr1, w2a, b2a, w2b, b2b, h2, AGM,
        pos1, pos2, nbr2, MM2, 0.4 * 0.4);
    // K4: agg2 (h2, nbr2 -> x2)
    agg_kernel<<<AG2, 256, 0, stream>>>(h2, nbr2, x2, MM1, MM2, 128);
    // K5: head
    head_kernel<<<BATCH, 256, 0, stream>>>(x2, w3a, b3a, w3b, b3b, fc1w, fc1b, fc2w, fc2b,
                                           (float*)d_out);
}